// Round 1
// baseline (304.063 us; speedup 1.0000x reference)
//
#include <hip/hip_runtime.h>
#include <hip/hip_bf16.h>

// GeneralConv: out[i[e]] += (group-wise 16x16 GEMV, weight slice k[e]) of input[j[e]], + bias.
// N=100000, E=2000000, C=64, K=27, G=4.
//
// Pipeline: fused prep (zero counts + bf16 weight repack + bf16 x convert),
// rank (fetch-add per edge) -> 3-phase multi-block scan -> fill (atomic-free
// CSR build), then node-parallel gather: zero atomics, v_dot2_f32_bf16.
//
// R1 change: gather inner loop now issues its 8 x-gather loads as inline-asm
// global_load_dwordx4 (volatile => cannot be serialized by the scheduler),
// waits once with vmcnt(0)+sched_barrier, and consumes weights per-edge so
// peak live registers fit the 64-VGPR / 8-waves-per-EU budget. Previous
// build showed VGPR_Count=32 => the 8 loads were never concurrently in
// flight => latency-bound (VALUBusy 34%).

#define KPOS 27
#define WPACK_UINTS (KPOS * 512)     // [k][q][gc][m] bf16-pairs: 13824 uints = 55296 B
#define SCAN_NB 256                   // blocks in multi-block scan

typedef unsigned u32x4 __attribute__((ext_vector_type(4)));

__device__ __forceinline__ unsigned packbf(float a, float b) {
    unsigned ua = (unsigned)__bfloat16_as_ushort(__float2bfloat16(a));
    unsigned ub = (unsigned)__bfloat16_as_ushort(__float2bfloat16(b));
    return ua | (ub << 16);
}

// acc += bf16lo(x)*bf16lo(w) + bf16hi(x)*bf16hi(w)  -- one VOP3P instruction
#define DOT2(A, X, W) asm("v_dot2_f32_bf16 %0, %1, %2, %0" : "+v"(A) : "v"(X), "v"(W))

// forced-concurrent 16B gather: dst <- xb[voff], xb base in SGPRs
#define GLOAD(DST, VOFF, BASE) \
    asm volatile("global_load_dwordx4 %0, %1, %2" : "=v"(DST) : "v"(VOFF), "s"(BASE))
#define GLOAD16(DST, VOFF, BASE) \
    asm volatile("global_load_dwordx4 %0, %1, %2 offset:16" : "=v"(DST) : "v"(VOFF), "s"(BASE))

// ---------- fallback (used only if ws too small) ----------
__global__ void init_out_kernel(float* __restrict__ out, const float* __restrict__ bias, int total) {
    int idx = blockIdx.x * blockDim.x + threadIdx.x;
    if (idx < total) out[idx] = bias[idx & 63];
}
__global__ void edge_kernel_rawW(const float* __restrict__ input, const int* __restrict__ ei,
                                 const int* __restrict__ ej, const int* __restrict__ ek,
                                 const float* __restrict__ weight, float* __restrict__ out, int n_edges) {
    const int lane = threadIdx.x & 63;
    const int g16 = lane & 48;
    const int d = lane & 15;
    int wave = (blockIdx.x * blockDim.x + threadIdx.x) >> 6;
    int n_waves = (gridDim.x * blockDim.x) >> 6;
    for (int e = wave; e < n_edges; e += n_waves) {
        int ie = ei[e], je = ej[e], ke = ek[e];
        float x = input[je * 64 + lane];
        float acc = 0.0f;
        #pragma unroll
        for (int c = 0; c < 16; ++c)
            acc += __shfl(x, g16 + c, 64) * weight[(g16 + c) * 432 + d * 27 + ke];
        atomicAdd(out + ie * 64 + lane, acc);
    }
}

// ---------- fused prep: zero counts, repack weights, convert x ----------
__global__ void prep_kernel(const float* __restrict__ input, const float* __restrict__ weight,
                            unsigned* __restrict__ xb, unsigned* __restrict__ wp,
                            int* __restrict__ cnt, int n_nodes, int nquads) {
    int t = blockIdx.x * blockDim.x + threadIdx.x;
    if (t < n_nodes) cnt[t] = 0;
    if (t < WPACK_UINTS) {
        int k  = t >> 9;
        int r  = t & 511;
        int q  = r >> 8;
        int r2 = r & 255;
        int gc = r2 >> 2;
        int m  = r2 & 3;
        int g = gc >> 4, d = gc & 15;
        int c = (q * 4 + m) * 2;
        int ic = g * 16 + c;
        float f0 = weight[ic * 432 + d * 27 + k];
        float f1 = weight[(ic + 1) * 432 + d * 27 + k];
        wp[t] = packbf(f0, f1);
    }
    if (t < nquads) {
        const float4* in4 = (const float4*)input;
        float4 a = in4[2 * t], b = in4[2 * t + 1];
        uint4 o;
        o.x = packbf(a.x, a.y);
        o.y = packbf(a.z, a.w);
        o.z = packbf(b.x, b.y);
        o.w = packbf(b.z, b.w);
        ((uint4*)xb)[t] = o;
    }
}

// ---------- sort pipeline ----------
__global__ void rank_kernel(const int* __restrict__ ei, int* __restrict__ cnt,
                            unsigned short* __restrict__ rank, int n_edges) {
    int e = blockIdx.x * blockDim.x + threadIdx.x;
    if (e < n_edges)
        rank[e] = (unsigned short)atomicAdd(&cnt[ei[e]], 1);
}

// phase A: per-block partial sums of cnt chunks
__global__ void scanA_kernel(const int* __restrict__ cnt, int* __restrict__ partial,
                             int n, int chunk) {
    __shared__ int red[256];
    int b = blockIdx.x;
    int lo = b * chunk, hi = min(lo + chunk, n);
    int s = 0;
    for (int v = lo + threadIdx.x; v < hi; v += 256) s += cnt[v];
    red[threadIdx.x] = s;
    __syncthreads();
    for (int d = 128; d > 0; d >>= 1) {
        if (threadIdx.x < d) red[threadIdx.x] += red[threadIdx.x + d];
        __syncthreads();
    }
    if (threadIdx.x == 0) partial[b] = red[0];
}

// phase B: single tiny block scans SCAN_NB partials (exclusive), writes off[n]=total
__global__ void scanB_kernel(int* __restrict__ partial, int* __restrict__ off, int n) {
    __shared__ int sums[SCAN_NB];
    int t = threadIdx.x;
    sums[t] = partial[t];
    __syncthreads();
    for (int d = 1; d < SCAN_NB; d <<= 1) {
        int val = (t >= d) ? sums[t - d] : 0;
        __syncthreads();
        sums[t] += val;
        __syncthreads();
    }
    partial[t] = (t == 0) ? 0 : sums[t - 1];   // exclusive
    if (t == SCAN_NB - 1) off[n] = sums[t];
}

// phase C: per-block exclusive scan of its chunk, offset by partial[b]
__global__ void scanC_kernel(const int* __restrict__ cnt, const int* __restrict__ partial,
                             int* __restrict__ off, int n, int chunk) {
    __shared__ int excl[256];
    int b = blockIdx.x;
    int lo = b * chunk, hi = min(lo + chunk, n);
    int per = (chunk + 255) >> 8;
    int tlo = lo + threadIdx.x * per;
    int thi = min(tlo + per, hi);
    int s = 0;
    for (int v = tlo; v < thi; ++v) s += cnt[v];
    excl[threadIdx.x] = s;
    __syncthreads();
    for (int d = 1; d < 256; d <<= 1) {
        int val = (threadIdx.x >= d) ? excl[threadIdx.x - d] : 0;
        __syncthreads();
        excl[threadIdx.x] += val;
        __syncthreads();
    }
    int run = partial[b] + ((threadIdx.x == 0) ? 0 : excl[threadIdx.x - 1]);
    for (int v = tlo; v < thi; ++v) { off[v] = run; run += cnt[v]; }
}

__global__ void fill_kernel(const int* __restrict__ ei, const int* __restrict__ ej,
                            const int* __restrict__ ek, const int* __restrict__ off,
                            const unsigned short* __restrict__ rank,
                            unsigned* __restrict__ jk, int n_edges) {
    int e = blockIdx.x * blockDim.x + threadIdx.x;
    if (e < n_edges)
        jk[off[ei[e]] + (int)rank[e]] = (unsigned)ej[e] | ((unsigned)ek[e] << 17);
}

// ---------- gather: one wave per node, no atomics, forced 8-deep MLP ----------
__launch_bounds__(1024, 8)
__global__ void gather_kernel(const unsigned* __restrict__ xb,
                              const unsigned* __restrict__ jk,
                              const int* __restrict__ off,
                              const unsigned* __restrict__ wp,
                              const float* __restrict__ bias,
                              float* __restrict__ out, int n) {
    __shared__ unsigned lds[WPACK_UINTS];
    for (int t = threadIdx.x; t < WPACK_UINTS / 4; t += blockDim.x)
        ((uint4*)lds)[t] = ((const uint4*)wp)[t];
    __syncthreads();

    const int lane = threadIdx.x & 63;
    const unsigned gby = (unsigned)((lane & 48) << 1);  // byte offset of group within node's 128B
    const float b  = bias[lane];
    const unsigned* wl = lds + (lane << 2);

    int wid = (blockIdx.x * blockDim.x + threadIdx.x) >> 6;
    int nw  = (gridDim.x * blockDim.x) >> 6;

    for (int v = wid; v < n; v += nw) {
        int e0 = off[v];
        int e1 = off[v + 1];
        float a0l = 0.0f, a0h = 0.0f, a1l = 0.0f, a1h = 0.0f;
        int e = e0;

        // 4-edge batch: 8 asm loads issued back-to-back (true MLP), one wait,
        // then per-edge LDS weight fetch + 8 dot2s (keeps live regs ~<64).
        for (; e + 4 <= e1; e += 4) {
            unsigned p0 = jk[e], p1 = jk[e + 1], p2 = jk[e + 2], p3 = jk[e + 3];
            unsigned o0 = ((p0 & 0x1FFFFu) << 7) + gby;
            unsigned o1 = ((p1 & 0x1FFFFu) << 7) + gby;
            unsigned o2 = ((p2 & 0x1FFFFu) << 7) + gby;
            unsigned o3 = ((p3 & 0x1FFFFu) << 7) + gby;
            u32x4 xa0, xc0, xa1, xc1, xa2, xc2, xa3, xc3;
            GLOAD  (xa0, o0, xb);
            GLOAD16(xc0, o0, xb);
            GLOAD  (xa1, o1, xb);
            GLOAD16(xc1, o1, xb);
            GLOAD  (xa2, o2, xb);
            GLOAD16(xc2, o2, xb);
            GLOAD  (xa3, o3, xb);
            GLOAD16(xc3, o3, xb);
            asm volatile("s_waitcnt vmcnt(0)");
            __builtin_amdgcn_sched_barrier(0);
            {
                const u32x4* wr = (const u32x4*)(wl + ((p0 >> 17) << 9));
                u32x4 wa = wr[0], wb = wr[64];
                DOT2(a0l, xa0[0], wa[0]); DOT2(a0h, xa0[1], wa[1]);
                DOT2(a0l, xa0[2], wa[2]); DOT2(a0h, xa0[3], wa[3]);
                DOT2(a0l, xc0[0], wb[0]); DOT2(a0h, xc0[1], wb[1]);
                DOT2(a0l, xc0[2], wb[2]); DOT2(a0h, xc0[3], wb[3]);
            }
            {
                const u32x4* wr = (const u32x4*)(wl + ((p1 >> 17) << 9));
                u32x4 wa = wr[0], wb = wr[64];
                DOT2(a1l, xa1[0], wa[0]); DOT2(a1h, xa1[1], wa[1]);
                DOT2(a1l, xa1[2], wa[2]); DOT2(a1h, xa1[3], wa[3]);
                DOT2(a1l, xc1[0], wb[0]); DOT2(a1h, xc1[1], wb[1]);
                DOT2(a1l, xc1[2], wb[2]); DOT2(a1h, xc1[3], wb[3]);
            }
            {
                const u32x4* wr = (const u32x4*)(wl + ((p2 >> 17) << 9));
                u32x4 wa = wr[0], wb = wr[64];
                DOT2(a0l, xa2[0], wa[0]); DOT2(a0h, xa2[1], wa[1]);
                DOT2(a0l, xa2[2], wa[2]); DOT2(a0h, xa2[3], wa[3]);
                DOT2(a0l, xc2[0], wb[0]); DOT2(a0h, xc2[1], wb[1]);
                DOT2(a0l, xc2[2], wb[2]); DOT2(a0h, xc2[3], wb[3]);
            }
            {
                const u32x4* wr = (const u32x4*)(wl + ((p3 >> 17) << 9));
                u32x4 wa = wr[0], wb = wr[64];
                DOT2(a1l, xa3[0], wa[0]); DOT2(a1h, xa3[1], wa[1]);
                DOT2(a1l, xa3[2], wa[2]); DOT2(a1h, xa3[3], wa[3]);
                DOT2(a1l, xc3[0], wb[0]); DOT2(a1h, xc3[1], wb[1]);
                DOT2(a1l, xc3[2], wb[2]); DOT2(a1h, xc3[3], wb[3]);
            }
        }

#define EDGE_BODY(P, AL, AH)                                                \
        do {                                                                \
            unsigned p_ = (P);                                              \
            const u32x4* wr = (const u32x4*)(wl + ((p_ >> 17) << 9));       \
            const u32x4* xr = (const u32x4*)(xb + ((p_ & 0x1FFFFu) << 5) + (gby >> 2)); \
            u32x4 xa = xr[0], xc = xr[1];                                   \
            u32x4 wa = wr[0], wb = wr[64];                                  \
            DOT2(AL, xa[0], wa[0]); DOT2(AH, xa[1], wa[1]);                 \
            DOT2(AL, xa[2], wa[2]); DOT2(AH, xa[3], wa[3]);                 \
            DOT2(AL, xc[0], wb[0]); DOT2(AH, xc[1], wb[1]);                 \
            DOT2(AL, xc[2], wb[2]); DOT2(AH, xc[3], wb[3]);                 \
        } while (0)

        for (; e + 2 <= e1; e += 2) {
            unsigned p0 = jk[e], p1 = jk[e + 1];
            EDGE_BODY(p0, a0l, a0h);
            EDGE_BODY(p1, a1l, a1h);
        }
        if (e < e1) EDGE_BODY(jk[e], a0l, a0h);
#undef EDGE_BODY

        out[(v << 6) + lane] = (a0l + a0h) + (a1l + a1h) + b;
    }
}

static inline size_t al256(size_t x) { return (x + 255) & ~(size_t)255; }

extern "C" void kernel_launch(void* const* d_in, const int* in_sizes, int n_in,
                              void* d_out, int out_size, void* d_ws, size_t ws_size,
                              hipStream_t stream) {
    const float* input  = (const float*)d_in[0];
    const int*   ei     = (const int*)d_in[1];
    const int*   ej     = (const int*)d_in[2];
    const int*   ek     = (const int*)d_in[3];
    const float* weight = (const float*)d_in[5];
    const float* bias   = (const float*)d_in[6];

    const int n_edges = in_sizes[1];
    const int n_nodes = out_size / 64;

    // workspace layout
    size_t off_o  = 0;
    size_t off_s  = al256((size_t)(n_nodes + 1) * 4);
    size_t cnt_o  = off_o + off_s;
    size_t cnt_s  = al256((size_t)n_nodes * 4);
    size_t par_o  = cnt_o + cnt_s;
    size_t par_s  = al256((size_t)SCAN_NB * 4);
    size_t rank_o = par_o + par_s;
    size_t rank_s = al256((size_t)n_edges * 2);
    size_t jk_o   = rank_o + rank_s;
    size_t jk_s   = al256((size_t)n_edges * 4);
    size_t wp_o   = jk_o + jk_s;
    size_t wp_s   = al256((size_t)WPACK_UINTS * 4);
    size_t xb_o   = wp_o + wp_s;
    size_t xb_s   = al256((size_t)n_nodes * 64 * 2);
    size_t need   = xb_o + xb_s;

    if (ws_size < need) {
        int blocks = (out_size + 255) / 256;
        hipLaunchKernelGGL(init_out_kernel, dim3(blocks), dim3(256), 0, stream,
                           (float*)d_out, bias, out_size);
        hipLaunchKernelGGL(edge_kernel_rawW, dim3(2048), dim3(256), 0, stream,
                           input, ei, ej, ek, weight, (float*)d_out, n_edges);
        return;
    }

    char* ws = (char*)d_ws;
    int*            off  = (int*)(ws + off_o);
    int*            cnt  = (int*)(ws + cnt_o);
    int*            par  = (int*)(ws + par_o);
    unsigned short* rank = (unsigned short*)(ws + rank_o);
    unsigned*       jk   = (unsigned*)(ws + jk_o);
    unsigned*       wp   = (unsigned*)(ws + wp_o);
    unsigned*       xb   = (unsigned*)(ws + xb_o);

    const int eb = (n_edges + 255) / 256;
    const int nquads = n_nodes * 8;
    const int prep_range = max(nquads, max(n_nodes, WPACK_UINTS));
    const int chunk = (n_nodes + SCAN_NB - 1) / SCAN_NB;

    // 1) fused prep: zero counts + repack weights + convert x
    hipLaunchKernelGGL(prep_kernel, dim3((prep_range + 255) / 256), dim3(256), 0, stream,
                       input, weight, xb, wp, cnt, n_nodes, nquads);
    // 2) counting sort -> CSR (atomic-free fill)
    hipLaunchKernelGGL(rank_kernel, dim3(eb), dim3(256), 0, stream, ei, cnt, rank, n_edges);
    hipLaunchKernelGGL(scanA_kernel, dim3(SCAN_NB), dim3(256), 0, stream, cnt, par, n_nodes, chunk);
    hipLaunchKernelGGL(scanB_kernel, dim3(1), dim3(SCAN_NB), 0, stream, par, off, n_nodes);
    hipLaunchKernelGGL(scanC_kernel, dim3(SCAN_NB), dim3(256), 0, stream, cnt, par, off, n_nodes, chunk);
    hipLaunchKernelGGL(fill_kernel, dim3(eb), dim3(256), 0, stream, ei, ej, ek, off, rank, jk, n_edges);

    // 3) gather-accumulate, one wave per node, no atomics
    hipLaunchKernelGGL(gather_kernel, dim3(512), dim3(1024), 0, stream,
                       xb, jk, off, wp, bias, (float*)d_out, n_nodes);
}